// Round 1
// baseline (455.244 us; speedup 1.0000x reference)
//
#include <hip/hip_runtime.h>
#include <hip/hip_bf16.h>

#define TT 4096
#define DD 1024
#define TBB 1024
#define WBB 256

typedef __attribute__((ext_vector_type(8))) _Float16 half8;
typedef __attribute__((ext_vector_type(4))) _Float16 half4;
typedef __attribute__((ext_vector_type(16))) float f32x16;

__device__ __forceinline__ unsigned short f2h(float v) {
  _Float16 h = (_Float16)v;
  return *reinterpret_cast<unsigned short*>(&h);
}
__device__ __forceinline__ float h2f(unsigned short u) {
  _Float16 h = *reinterpret_cast<_Float16*>(&u);
  return (float)h;
}

__device__ __forceinline__ void gl_lds16(const unsigned short* g, unsigned short* l) {
  __builtin_amdgcn_global_load_lds(
      (const __attribute__((address_space(1))) void*)(unsigned long long)(g),
      (__attribute__((address_space(3))) void*)(unsigned long long)(l),
      16, 0, 0);
}

__device__ __forceinline__ float waveSum(float v) {
#pragma unroll
  for (int o = 32; o > 0; o >>= 1) v += __shfl_down(v, o, 64);
  return v;
}
// Butterfly versions: result valid in ALL lanes (needed for wave-per-row stats).
__device__ __forceinline__ float bSum(float v) {
#pragma unroll
  for (int o = 32; o > 0; o >>= 1) v += __shfl_xor(v, o, 64);
  return v;
}
__device__ __forceinline__ float bMax(float v) {
#pragma unroll
  for (int o = 32; o > 0; o >>= 1) v = fmaxf(v, __shfl_xor(v, o, 64));
  return v;
}

// Generic C = A (MxK) * B^T, fp16, 128x128 tile, 4 waves, BK=64,
// mfma 32x32x16 f16, XOR bank swizzle. (r5-verified best core; used for QKV.)
// EPI: 0 plain
template <int EPI, typename OutT>
__global__ __launch_bounds__(256) void gemm_bt(
    const unsigned short* __restrict__ A, const unsigned short* __restrict__ B,
    OutT* __restrict__ C,
    int K, int lda, int ldb, int ldc,
    int zbase, int zdiv,
    long sAi, long sAj, long sBi, long sBj, long sCi, long sCj,
    long sAz, long sBz, long sCz,
    const float* __restrict__ e0, const float* __restrict__ e1,
    const float* __restrict__ e2, const float* __restrict__ e3,
    const float* __restrict__ e4)
{
  __shared__ __align__(16) unsigned short lA[2][4096];
  __shared__ __align__(16) unsigned short lB[2][4096];

  const int z = blockIdx.z, gz = zbase + z;
  const int zi = gz / zdiv, zj = gz - zi * zdiv;
  const unsigned short* Ab = A + (long)zi * sAi + (long)zj * sAj + (long)z * sAz;
  const unsigned short* Bb = B + (long)zi * sBi + (long)zj * sBj + (long)z * sBz;
  const long offC = (long)zi * sCi + (long)zj * sCj + (long)z * sCz;

  const int m0 = blockIdx.y * 128, n0 = blockIdx.x * 128;
  const int tid = threadIdx.x, wave = tid >> 6, lane = tid & 63;
  const int wm = (wave >> 1) * 64, wn = (wave & 1) * 64;
  const int srow = lane >> 2;
  const int scol = (((lane & 3) ^ ((srow >> 1) & 3))) * 8;
  const int l31 = lane & 31, khi = lane >> 5;
  const int sw2 = (l31 >> 1) & 3;

  f32x16 acc[2][2] = {};

  for (int k0 = 0; k0 < K; k0 += 64) {
#pragma unroll
    for (int h = 0; h < 2; ++h)
#pragma unroll
      for (int t = 0; t < 2; ++t) {
        const int r = wave * 32 + t * 16 + srow;
        gl_lds16(Ab + (long)(m0 + r) * lda + (k0 + h * 32 + scol), &lA[h][wave * 1024 + t * 512]);
        gl_lds16(Bb + (long)(n0 + r) * ldb + (k0 + h * 32 + scol), &lB[h][wave * 1024 + t * 512]);
      }
    __syncthreads();

    half8 af[2][4], bfr[2][4];
#pragma unroll
    for (int mi = 0; mi < 2; ++mi)
#pragma unroll
      for (int ks = 0; ks < 4; ++ks)
        af[mi][ks] = *(const half8*)&lA[ks >> 1][(wm + mi * 32 + l31) * 32 + ((((ks & 1) * 2 + khi) ^ sw2) * 8)];
#pragma unroll
    for (int ni = 0; ni < 2; ++ni)
#pragma unroll
      for (int ks = 0; ks < 4; ++ks)
        bfr[ni][ks] = *(const half8*)&lB[ks >> 1][(wn + ni * 32 + l31) * 32 + ((((ks & 1) * 2 + khi) ^ sw2) * 8)];

#pragma unroll
    for (int ks = 0; ks < 4; ++ks)
#pragma unroll
      for (int mi = 0; mi < 2; ++mi)
#pragma unroll
        for (int ni = 0; ni < 2; ++ni)
          acc[mi][ni] = __builtin_amdgcn_mfma_f32_32x32x16_f16(af[mi][ks], bfr[ni][ks], acc[mi][ni], 0, 0, 0);
    __syncthreads();
  }

  OutT* Cb = C + offC;
#pragma unroll
  for (int mi = 0; mi < 2; ++mi)
#pragma unroll
    for (int ni = 0; ni < 2; ++ni)
#pragma unroll
      for (int r = 0; r < 16; ++r) {
        const int row = m0 + wm + mi * 32 + khi * 4 + (r & 3) + 8 * (r >> 2);
        const int col = n0 + wn + ni * 32 + l31;
        float v = acc[mi][ni][r];
        const long ci = (long)row * ldc + col;
        if constexpr (sizeof(OutT) == 2) {
          Cb[ci] = (OutT)f2h(v);
        } else {
          Cb[ci] = v;
        }
      }
}

// Small-tile GEMM for occupancy: 64x64 tile, 4 waves (each one 32x32 quadrant),
// BK=64, swizzled LDS (16 KB), grid 4x larger than 128-tile -> 4 blocks/CU.
// EPI: 0 plain, 1 -> 1-acc, 3 -> +ent/dep cols (ent unnormalized; scale=1/e4[gz])
template <int EPI, typename OutT>
__global__ __launch_bounds__(256) void gemm_s(
    const unsigned short* __restrict__ A, const unsigned short* __restrict__ B,
    OutT* __restrict__ C,
    int K, int lda, int ldb, int ldc,
    int zbase, int zdiv,
    long sAi, long sAj, long sBi, long sBj, long sCi, long sCj,
    long sAz, long sBz, long sCz,
    const float* __restrict__ e0, const float* __restrict__ e1,
    const float* __restrict__ e2, const float* __restrict__ e3,
    const float* __restrict__ e4)
{
  __shared__ __align__(16) unsigned short lA[2][2048];
  __shared__ __align__(16) unsigned short lB[2][2048];

  const int z = blockIdx.z, gz = zbase + z;
  const int zi = gz / zdiv, zj = gz - zi * zdiv;
  const unsigned short* Ab = A + (long)zi * sAi + (long)zj * sAj + (long)z * sAz;
  const unsigned short* Bb = B + (long)zi * sBi + (long)zj * sBj + (long)z * sBz;
  const long offC = (long)zi * sCi + (long)zj * sCj + (long)z * sCz;

  const int m0 = blockIdx.y * 64, n0 = blockIdx.x * 64;
  const int tid = threadIdx.x, wave = tid >> 6, lane = tid & 63;
  const int wm = (wave >> 1) * 32, wn = (wave & 1) * 32;
  const int srow = lane >> 2;                       // staging row within wave's 16-row slice
  const int grow = wave * 16 + srow;                // global staging row 0..63
  const int scol = (((lane & 3) ^ ((grow >> 1) & 3))) * 8;
  const int l31 = lane & 31, khi = lane >> 5;
  const int sw2 = (l31 >> 1) & 3;

  float esc = 0.f;
  if constexpr (EPI == 3) esc = 1.f / fmaxf(e4[gz], 1e-12f);

  f32x16 acc = {};

  for (int k0 = 0; k0 < K; k0 += 64) {
#pragma unroll
    for (int h = 0; h < 2; ++h) {
      gl_lds16(Ab + (long)(m0 + grow) * lda + (k0 + h * 32 + scol), &lA[h][wave * 512]);
      gl_lds16(Bb + (long)(n0 + grow) * ldb + (k0 + h * 32 + scol), &lB[h][wave * 512]);
    }
    __syncthreads();

    half8 af[4], bfr[4];
#pragma unroll
    for (int ks = 0; ks < 4; ++ks) {
      af[ks] = *(const half8*)&lA[ks >> 1][(wm + l31) * 32 + ((((ks & 1) * 2 + khi) ^ sw2) * 8)];
      bfr[ks] = *(const half8*)&lB[ks >> 1][(wn + l31) * 32 + ((((ks & 1) * 2 + khi) ^ sw2) * 8)];
    }
#pragma unroll
    for (int ks = 0; ks < 4; ++ks)
      acc = __builtin_amdgcn_mfma_f32_32x32x16_f16(af[ks], bfr[ks], acc, 0, 0, 0);
    __syncthreads();
  }

  OutT* Cb = C + offC;
#pragma unroll
  for (int r = 0; r < 16; ++r) {
    const int row = m0 + wm + khi * 4 + (r & 3) + 8 * (r >> 2);
    const int col = n0 + wn + l31;
    float v = acc[r];
    if constexpr (EPI == 1) v = 1.0f - v;
    if constexpr (EPI == 3)
      v += e0[(long)gz * 1024 + row] * esc * e2[col] + e1[(long)gz * 1024 + row] * e3[col];
    const long ci = (long)row * ldc + col;
    if constexpr (sizeof(OutT) == 2) {
      Cb[ci] = (OutT)f2h(v);
    } else {
      Cb[ci] = v;
    }
  }
}

// sim GEMM: C(fp16) = A*B^T + APh, 128x128, LDS-staged, swizzled. (4/CU already.)
__global__ __launch_bounds__(256) void sim_gemm(
    const unsigned short* __restrict__ A, const unsigned short* __restrict__ B,
    unsigned short* __restrict__ C,
    const unsigned short* __restrict__ APh)
{
  __shared__ __align__(16) unsigned short lA[2][4096];
  __shared__ __align__(16) unsigned short lB[2][4096];

  const int gz = blockIdx.z;
  const int zi = gz >> 2, zj = gz & 3;
  const unsigned short* Ab = A + (long)zi * (TBB * DD) + zj * WBB;
  const unsigned short* Bb = B + (long)zi * (TBB * DD) + zj * WBB;
  unsigned short* Cb = C + (long)gz * TBB * TBB;

  const int m0 = blockIdx.y * 128, n0 = blockIdx.x * 128;
  const int tid = threadIdx.x, wave = tid >> 6, lane = tid & 63;
  const int wm = (wave >> 1) * 64, wn = (wave & 1) * 64;
  const int srow = lane >> 2;
  const int scol = ((lane & 3) ^ ((srow >> 1) & 3)) * 8;
  const int l31 = lane & 31, khi = lane >> 5;
  const int sw2 = (l31 >> 1) & 3;

  f32x16 acc[2][2] = {};

  for (int k0 = 0; k0 < WBB; k0 += 64) {
#pragma unroll
    for (int h = 0; h < 2; ++h)
#pragma unroll
      for (int t = 0; t < 2; ++t) {
        const int r = wave * 32 + t * 16 + srow;
        gl_lds16(Ab + (long)(m0 + r) * DD + (k0 + h * 32 + scol), &lA[h][wave * 1024 + t * 512]);
        gl_lds16(Bb + (long)(n0 + r) * DD + (k0 + h * 32 + scol), &lB[h][wave * 1024 + t * 512]);
      }
    __syncthreads();

    half8 af[2][4], bfr[2][4];
#pragma unroll
    for (int mi = 0; mi < 2; ++mi)
#pragma unroll
      for (int ks = 0; ks < 4; ++ks)
        af[mi][ks] = *(const half8*)&lA[ks >> 1][(wm + mi * 32 + l31) * 32 + ((((ks & 1) * 2 + khi) ^ sw2) * 8)];
#pragma unroll
    for (int ni = 0; ni < 2; ++ni)
#pragma unroll
      for (int ks = 0; ks < 4; ++ks)
        bfr[ni][ks] = *(const half8*)&lB[ks >> 1][(wn + ni * 32 + l31) * 32 + ((((ks & 1) * 2 + khi) ^ sw2) * 8)];

#pragma unroll
    for (int ks = 0; ks < 4; ++ks)
#pragma unroll
      for (int mi = 0; mi < 2; ++mi)
#pragma unroll
        for (int ni = 0; ni < 2; ++ni)
          acc[mi][ni] = __builtin_amdgcn_mfma_f32_32x32x16_f16(af[mi][ks], bfr[ni][ks], acc[mi][ni], 0, 0, 0);
    __syncthreads();
  }

#pragma unroll
  for (int mi = 0; mi < 2; ++mi)
#pragma unroll
    for (int ni = 0; ni < 2; ++ni)
#pragma unroll
      for (int r = 0; r < 16; ++r) {
        const int row = m0 + wm + mi * 32 + khi * 4 + (r & 3) + 8 * (r >> 2);
        const int col = n0 + wn + ni * 32 + l31;
        Cb[(long)row * TBB + col] = f2h(acc[mi][ni][r] + h2f(APh[(long)row * 1024 + col]));
      }
}

// ctx = (attw * (1+dep[k])) @ Vb, 64x64 tile.
// attw recomputed on the fly from sim(fp16) + per-row B = (m + ln L)*log2e:
//   attw = exp2(s*log2e - B)   (removes the 32MB wpre buffer entirely)
__global__ __launch_bounds__(256) void ctx_gemm_s(
    const unsigned short* __restrict__ simh, const float* __restrict__ dep,
    const float* __restrict__ Brow,
    const unsigned short* __restrict__ Vt, unsigned short* __restrict__ ctx)
{
  __shared__ __align__(16) unsigned short lA[2][2048];
  __shared__ __align__(16) unsigned short lB[2][2048];
  __shared__ __align__(16) unsigned short sDepH[1024];

  const int gz = blockIdx.z, zi = gz >> 2, zj = gz & 3;
  const int m0 = blockIdx.y * 64, n0 = blockIdx.x * 64;
  const int tid = threadIdx.x, wave = tid >> 6, lane = tid & 63;
  const int wm = (wave >> 1) * 32, wn = (wave & 1) * 32;
  const int srow = lane >> 2;
  const int grow = wave * 16 + srow;
  const int scol = ((lane & 3) ^ ((grow >> 1) & 3)) * 8;
  const int l31 = lane & 31, khi = lane >> 5;
  const int sw2 = (l31 >> 1) & 3;

#pragma unroll
  for (int p = 0; p < 4; ++p)
    sDepH[tid + p * 256] = f2h(1.f + dep[(long)gz * 1024 + tid + p * 256]);
  __syncthreads();

  // per-thread softmax row constants (row fixed per p across all k-steps)
  const float B0 = Brow[(long)gz * 1024 + m0 + (tid >> 3)];
  const float B1 = Brow[(long)gz * 1024 + m0 + 32 + (tid >> 3)];

  const unsigned short* Ab = simh + (long)gz * TBB * TBB;
  const unsigned short* Bb = Vt + (long)(zj * 256) * TT + (long)zi * 1024;

  f32x16 acc = {};

  for (int k0 = 0; k0 < 1024; k0 += 64) {
#pragma unroll
    for (int h = 0; h < 2; ++h)
      gl_lds16(Bb + (long)(n0 + grow) * TT + (k0 + h * 32 + scol), &lB[h][wave * 512]);
#pragma unroll
    for (int h = 0; h < 2; ++h)
#pragma unroll
      for (int p = 0; p < 2; ++p) {
        const int idx = p * 1024 + tid * 4;
        const int row = idx >> 5, col = idx & 31;
        const ushort4 wv = *(const ushort4*)(Ab + (long)(m0 + row) * 1024 + k0 + h * 32 + col);
        const float Bp = p ? B1 : B0;
        half4 ev;
        ev.x = (_Float16)exp2f(fmaf(h2f(wv.x), 1.4426950408889634f, -Bp));
        ev.y = (_Float16)exp2f(fmaf(h2f(wv.y), 1.4426950408889634f, -Bp));
        ev.z = (_Float16)exp2f(fmaf(h2f(wv.z), 1.4426950408889634f, -Bp));
        ev.w = (_Float16)exp2f(fmaf(h2f(wv.w), 1.4426950408889634f, -Bp));
        const half4 dv = *(const half4*)&sDepH[k0 + h * 32 + col];
        half4 pv = ev * dv;
        const int pcol = (((col >> 3) ^ ((row >> 1) & 3)) << 3) | (col & 7);
        *(half4*)&lA[h][row * 32 + pcol] = pv;
      }
    __syncthreads();

    half8 af[4], bfr[4];
#pragma unroll
    for (int ks = 0; ks < 4; ++ks) {
      af[ks] = *(const half8*)&lA[ks >> 1][(wm + l31) * 32 + ((((ks & 1) * 2 + khi) ^ sw2) * 8)];
      bfr[ks] = *(const half8*)&lB[ks >> 1][(wn + l31) * 32 + ((((ks & 1) * 2 + khi) ^ sw2) * 8)];
    }
#pragma unroll
    for (int ks = 0; ks < 4; ++ks)
      acc = __builtin_amdgcn_mfma_f32_32x32x16_f16(af[ks], bfr[ks], acc, 0, 0, 0);
    __syncthreads();
  }

  unsigned short* Cb = ctx + (long)gz * TBB * WBB;
#pragma unroll
  for (int r = 0; r < 16; ++r) {
    const int row = m0 + wm + khi * 4 + (r & 3) + 8 * (r >> 2);
    const int col = n0 + wn + l31;
    Cb[(long)row * WBB + col] = f2h(acc[r]);
  }
}

__global__ __launch_bounds__(256) void prepx_kernel(
    const float* __restrict__ x, unsigned short* __restrict__ xh,
    unsigned short* __restrict__ xu)
{
  const int t = blockIdx.x, tid = threadIdx.x;
  const float4 v = *((const float4*)(x + (long)t * DD) + tid);
  float ss = v.x * v.x + v.y * v.y + v.z * v.z + v.w * v.w;
  ss = waveSum(ss);
  __shared__ float red[4];
  if ((tid & 63) == 0) red[tid >> 6] = ss;
  __syncthreads();
  const float tot = red[0] + red[1] + red[2] + red[3];
  const float inv = 1.f / fmaxf(sqrtf(tot), 1e-12f);
  ushort4 h, u;
  h.x = f2h(v.x); h.y = f2h(v.y); h.z = f2h(v.z); h.w = f2h(v.w);
  u.x = f2h(v.x * inv); u.y = f2h(v.y * inv); u.z = f2h(v.z * inv); u.w = f2h(v.w * inv);
  *((ushort4*)(xh + (long)t * DD) + tid) = h;
  *((ushort4*)(xu + (long)t * DD) + tid) = u;
}

// Merged fp32->fp16 cast for Wq|Wk|Wv (-> Wh) and Wout (-> WoB). One launch.
__global__ __launch_bounds__(256) void castall_kernel(
    const float* __restrict__ Wq, const float* __restrict__ Wk,
    const float* __restrict__ Wv, const float* __restrict__ Wo,
    unsigned short* __restrict__ Wh, unsigned short* __restrict__ WoB)
{
  const long idx4 = ((long)blockIdx.x * 256 + threadIdx.x) * 4;
  const int which = (int)(idx4 >> 20);
  const long loc = idx4 & ((1L << 20) - 1);
  const float* src = (which == 0) ? Wq : ((which == 1) ? Wk : ((which == 2) ? Wv : Wo));
  unsigned short* dst = (which < 3) ? (Wh + idx4) : (WoB + loc);
  const float4 v = *(const float4*)(src + loc);
  ushort4 h;
  h.x = f2h(v.x); h.y = f2h(v.y); h.z = f2h(v.z); h.w = f2h(v.w);
  *(ushort4*)dst = h;
}

__global__ __launch_bounds__(256) void packw2_kernel(
    const float* __restrict__ W2, unsigned short* __restrict__ W2B,
    float* __restrict__ Ecol, float* __restrict__ Dcol,
    float* __restrict__ entsum)
{
  const int c = blockIdx.x, j = threadIdx.x;
  W2B[c * 256 + j] = f2h(W2[c * 258 + j]);
  if (j == 0) {
    Ecol[c] = W2[c * 258 + 256];
    Dcol[c] = W2[c * 258 + 257];
  }
  if (c == 0 && j < 16) entsum[j] = 0.f;
}

__global__ __launch_bounds__(256) void ap_kernel(unsigned short* __restrict__ APh)
{
  const int p = blockIdx.x, tid = threadIdx.x;
#pragma unroll
  for (int t = 0; t < 4; ++t) {
    const int col = tid + t * 256;
    const int i = col >> 1;
    const float e = (2.0f * (float)i) / 1024.0f;
    // freq^-e = exp2(-e * log2(10000))
    const float ang = (float)p * exp2f(e * -13.287712379549449f);
    APh[(long)p * 1024 + col] = f2h((col & 1) ? cosf(ang) : sinf(ang));
  }
}

__global__ __launch_bounds__(256) void transpose_kernel(
    const unsigned short* __restrict__ V, unsigned short* __restrict__ Vt)
{
  __shared__ unsigned short tile[32][33];
  const int tx = threadIdx.x & 31, ty = threadIdx.x >> 5;
  const int c0 = blockIdx.x * 32;
  const int r0 = blockIdx.y * 32;
#pragma unroll
  for (int rr = ty; rr < 32; rr += 8)
    tile[rr][tx] = V[(long)(r0 + rr) * DD + c0 + tx];
  __syncthreads();
#pragma unroll
  for (int rr = ty; rr < 32; rr += 8)
    Vt[(long)(c0 + rr) * TT + r0 + tx] = tile[tx][rr];
}

// Wave-per-row stats: 4 rows/block, butterfly reductions, no LDS, no barriers.
// Outputs per row: dep, ent(raw), B=(m+lnL)*log2e; atomically accumulates sum|ent| per gz.
// No wpre write (ctx recomputes attw from sim + B).
__global__ __launch_bounds__(256) void stats_kernel(
    const unsigned short* __restrict__ sim, const unsigned short* __restrict__ divb,
    float* __restrict__ dep, float* __restrict__ ent,
    float* __restrict__ Brow, float* __restrict__ entsum)
{
  const int gz = blockIdx.y, bi = gz >> 2;
  const int wave = threadIdx.x >> 6, lane = threadIdx.x & 63;
  const int q = blockIdx.x * 4 + wave;
  const unsigned short* srow = sim + ((long)gz * TBB + q) * TBB;
  const unsigned short* drow = divb + ((long)bi * TBB + q) * TBB;
  float s[16], d[16];
#pragma unroll
  for (int u = 0; u < 4; ++u) {
    const ushort4 sv = *(const ushort4*)(srow + u * 256 + lane * 4);
    const ushort4 dv = *(const ushort4*)(drow + u * 256 + lane * 4);
    s[u * 4 + 0] = h2f(sv.x); s[u * 4 + 1] = h2f(sv.y);
    s[u * 4 + 2] = h2f(sv.z); s[u * 4 + 3] = h2f(sv.w);
    d[u * 4 + 0] = h2f(dv.x); d[u * 4 + 1] = h2f(dv.y);
    d[u * 4 + 2] = h2f(dv.z); d[u * 4 + 3] = h2f(dv.w);
  }
  float m = s[0];
#pragma unroll
  for (int i = 1; i < 16; ++i) m = fmaxf(m, s[i]);
  m = bMax(m);
  const float mB = m * 1.4426950408889634f;
  float l = 0.f, ss = 0.f, dn = 0.f, ds = 0.f;
#pragma unroll
  for (int i = 0; i < 16; ++i) {
    const float e = exp2f(fmaf(s[i], 1.4426950408889634f, -mB));
    l += e; ss += e * s[i]; dn += e * d[i]; ds += d[i];
  }
  l = bSum(l); ss = bSum(ss); dn = bSum(dn); ds = bSum(ds);
  if (lane == 0) {
    const long o = (long)gz * TBB + q;
    const float Li = 1.f / l;
    const float lnL = logf(l);
    dep[o] = (dn * Li) / ds;
    const float entv = (m + lnL - ss * Li) * 0.14426950408889634f;  // 1/ln(1024)
    ent[o] = entv;
    Brow[o] = (m + lnL) * 1.4426950408889634f;
    atomicAdd(&entsum[gz], fabsf(entv));
  }
}

extern "C" void kernel_launch(void* const* d_in, const int* in_sizes, int n_in,
                              void* d_out, int out_size, void* d_ws, size_t ws_size,
                              hipStream_t stream)
{
  const float* x  = (const float*)d_in[0];
  const float* Wq = (const float*)d_in[1];
  const float* Wk = (const float*)d_in[2];
  const float* Wv = (const float*)d_in[3];
  const float* Wo = (const float*)d_in[4];
  const float* W2 = (const float*)d_in[5];

  char* ws = (char*)d_ws;
  size_t off = 0;
  auto take = [&](size_t bytes) -> void* {
    void* p = ws + off;
    off += (bytes + 255) & ~(size_t)255;
    return p;
  };
  unsigned short* QKV = (unsigned short*)take((size_t)3 * TT * DD * 2);
  unsigned short* xh  = (unsigned short*)take((size_t)TT * DD * 2);
  unsigned short* xu  = (unsigned short*)take((size_t)TT * DD * 2);
  unsigned short* Wh  = (unsigned short*)take((size_t)3 * DD * DD * 2);
  unsigned short* WoB = (unsigned short*)take((size_t)DD * DD * 2);
  unsigned short* W2B = (unsigned short*)take((size_t)256 * 256 * 2);
  float* Ecol = (float*)take(256 * 4);
  float* Dcol = (float*)take(256 * 4);
  unsigned short* APh = (unsigned short*)take((size_t)TBB * TBB * 2);
  unsigned short* divb = (unsigned short*)take((size_t)4 * TBB * TBB * 2);
  unsigned short* Vt = (unsigned short*)take((size_t)DD * TT * 2);
  unsigned short* simh = (unsigned short*)take((size_t)16 * TBB * TBB * 2);
  float* depb = (float*)take((size_t)16 * TBB * 4);
  float* entb = (float*)take((size_t)16 * TBB * 4);
  float* Brow = (float*)take((size_t)16 * TBB * 4);
  float* entsum = (float*)take((size_t)16 * 4);
  unsigned short* ctx = (unsigned short*)take((size_t)16 * TBB * WBB * 2);
  unsigned short* Y = (unsigned short*)take((size_t)TT * DD * 2);
  (void)ws_size; (void)in_sizes; (void)n_in; (void)out_size;

  prepx_kernel<<<TT, 256, 0, stream>>>(x, xh, xu);
  castall_kernel<<<(4 * DD * DD) / 1024, 256, 0, stream>>>(Wq, Wk, Wv, Wo, Wh, WoB);
  packw2_kernel<<<256, 256, 0, stream>>>(W2, W2B, Ecol, Dcol, entsum);
  ap_kernel<<<TBB, 256, 0, stream>>>(APh);

  // QKV projection: 128-tile core (3 blocks/CU, best measured)
  gemm_bt<0, unsigned short><<<dim3(DD / 128, TT / 128, 3), 256, 0, stream>>>(
      xh, Wh, QKV,
      DD, DD, DD, DD, 0, 1,
      0, 0, (long)DD * DD, 0, (long)TT * DD, 0,
      0, 0, 0, nullptr, nullptr, nullptr, nullptr, nullptr);

  transpose_kernel<<<dim3(DD / 32, TT / 32), 256, 0, stream>>>(QKV + (size_t)2 * TT * DD, Vt);

  // div diagonal blocks: 1 - xu_i @ xu_i^T, fp16 out — 64-tile, 4 blocks/CU
  gemm_s<1, unsigned short><<<dim3(16, 16, 4), 256, 0, stream>>>(
      xu, xu, divb,
      DD, DD, DD, TBB, 0, 1,
      (long)TBB * DD, 0, (long)TBB * DD, 0, (long)TBB * TBB, 0,
      0, 0, 0, nullptr, nullptr, nullptr, nullptr, nullptr);

  const unsigned short* Qh = QKV;
  const unsigned short* Kh = QKV + (size_t)TT * DD;

  // sim = Qb @ Kb^T + APh (fp16 out), all 16 blocks (4 blocks/CU already)
  sim_gemm<<<dim3(8, 8, 16), 256, 0, stream>>>(Qh, Kh, simh, APh);

  // per-row softmax stats: dep, ent(raw), B; Σ|ent| per gz via atomics (replaces entnorm)
  stats_kernel<<<dim3(TBB / 4, 16), 256, 0, stream>>>(simh, divb, depb, entb, Brow, entsum);

  // ctx = (exp2(s*log2e - B) * (1+dep[k])) @ Vb — 64-tile, attw recomputed in staging
  ctx_gemm_s<<<dim3(4, 16, 16), 256, 0, stream>>>(simh, depb, Brow, Vt, ctx);

  // y = [ctx | ent | dep] @ Wout2^T — 64-tile, 4 blocks/CU (ent scale fused via entsum)
  gemm_s<3, unsigned short><<<dim3(4, 16, 16), 256, 0, stream>>>(
      ctx, W2B, Y,
      WBB, WBB, WBB, DD, 0, 4,
      (long)4 * TBB * WBB, (long)TBB * WBB, 0, 0, (long)TBB * DD, (long)WBB,
      0, 0, 0, entb, depb, Ecol, Dcol, entsum);

  // out = Y @ Wout^T — 64-tile, 4 blocks/CU
  gemm_s<0, float><<<dim3(16, 64, 1), 256, 0, stream>>>(
      Y, WoB, (float*)d_out,
      DD, DD, DD, DD, 0, 1,
      0, 0, 0, 0, 0, 0,
      0, 0, 0, nullptr, nullptr, nullptr, nullptr, nullptr);
}

// Round 2
// 251.534 us; speedup vs baseline: 1.8099x; 1.8099x over previous
//
#include <hip/hip_runtime.h>
#include <hip/hip_bf16.h>

#define TT 4096
#define DD 1024
#define TBB 1024
#define WBB 256

typedef __attribute__((ext_vector_type(8))) _Float16 half8;
typedef __attribute__((ext_vector_type(4))) _Float16 half4;
typedef __attribute__((ext_vector_type(16))) float f32x16;

__device__ __forceinline__ unsigned short f2h(float v) {
  _Float16 h = (_Float16)v;
  return *reinterpret_cast<unsigned short*>(&h);
}
__device__ __forceinline__ float h2f(unsigned short u) {
  _Float16 h = *reinterpret_cast<_Float16*>(&u);
  return (float)h;
}

__device__ __forceinline__ void gl_lds16(const unsigned short* g, unsigned short* l) {
  __builtin_amdgcn_global_load_lds(
      (const __attribute__((address_space(1))) void*)(unsigned long long)(g),
      (__attribute__((address_space(3))) void*)(unsigned long long)(l),
      16, 0, 0);
}

__device__ __forceinline__ float waveSum(float v) {
#pragma unroll
  for (int o = 32; o > 0; o >>= 1) v += __shfl_down(v, o, 64);
  return v;
}
// Butterfly versions: result valid in ALL lanes (needed for wave-per-row stats).
__device__ __forceinline__ float bSum(float v) {
#pragma unroll
  for (int o = 32; o > 0; o >>= 1) v += __shfl_xor(v, o, 64);
  return v;
}
__device__ __forceinline__ float bMax(float v) {
#pragma unroll
  for (int o = 32; o > 0; o >>= 1) v = fmaxf(v, __shfl_xor(v, o, 64));
  return v;
}

// Generic C = A (MxK) * B^T, fp16, 128x128 tile, 4 waves, BK=64,
// mfma 32x32x16 f16, XOR bank swizzle. (r5-verified best core; used for QKV.)
// EPI: 0 plain
template <int EPI, typename OutT>
__global__ __launch_bounds__(256) void gemm_bt(
    const unsigned short* __restrict__ A, const unsigned short* __restrict__ B,
    OutT* __restrict__ C,
    int K, int lda, int ldb, int ldc,
    int zbase, int zdiv,
    long sAi, long sAj, long sBi, long sBj, long sCi, long sCj,
    long sAz, long sBz, long sCz,
    const float* __restrict__ e0, const float* __restrict__ e1,
    const float* __restrict__ e2, const float* __restrict__ e3)
{
  __shared__ __align__(16) unsigned short lA[2][4096];
  __shared__ __align__(16) unsigned short lB[2][4096];

  const int z = blockIdx.z, gz = zbase + z;
  const int zi = gz / zdiv, zj = gz - zi * zdiv;
  const unsigned short* Ab = A + (long)zi * sAi + (long)zj * sAj + (long)z * sAz;
  const unsigned short* Bb = B + (long)zi * sBi + (long)zj * sBj + (long)z * sBz;
  const long offC = (long)zi * sCi + (long)zj * sCj + (long)z * sCz;

  const int m0 = blockIdx.y * 128, n0 = blockIdx.x * 128;
  const int tid = threadIdx.x, wave = tid >> 6, lane = tid & 63;
  const int wm = (wave >> 1) * 64, wn = (wave & 1) * 64;
  const int srow = lane >> 2;
  const int scol = (((lane & 3) ^ ((srow >> 1) & 3))) * 8;
  const int l31 = lane & 31, khi = lane >> 5;
  const int sw2 = (l31 >> 1) & 3;

  f32x16 acc[2][2] = {};

  for (int k0 = 0; k0 < K; k0 += 64) {
#pragma unroll
    for (int h = 0; h < 2; ++h)
#pragma unroll
      for (int t = 0; t < 2; ++t) {
        const int r = wave * 32 + t * 16 + srow;
        gl_lds16(Ab + (long)(m0 + r) * lda + (k0 + h * 32 + scol), &lA[h][wave * 1024 + t * 512]);
        gl_lds16(Bb + (long)(n0 + r) * ldb + (k0 + h * 32 + scol), &lB[h][wave * 1024 + t * 512]);
      }
    __syncthreads();

    half8 af[2][4], bfr[2][4];
#pragma unroll
    for (int mi = 0; mi < 2; ++mi)
#pragma unroll
      for (int ks = 0; ks < 4; ++ks)
        af[mi][ks] = *(const half8*)&lA[ks >> 1][(wm + mi * 32 + l31) * 32 + ((((ks & 1) * 2 + khi) ^ sw2) * 8)];
#pragma unroll
    for (int ni = 0; ni < 2; ++ni)
#pragma unroll
      for (int ks = 0; ks < 4; ++ks)
        bfr[ni][ks] = *(const half8*)&lB[ks >> 1][(wn + ni * 32 + l31) * 32 + ((((ks & 1) * 2 + khi) ^ sw2) * 8)];

#pragma unroll
    for (int ks = 0; ks < 4; ++ks)
#pragma unroll
      for (int mi = 0; mi < 2; ++mi)
#pragma unroll
        for (int ni = 0; ni < 2; ++ni)
          acc[mi][ni] = __builtin_amdgcn_mfma_f32_32x32x16_f16(af[mi][ks], bfr[ni][ks], acc[mi][ni], 0, 0, 0);
    __syncthreads();
  }

  OutT* Cb = C + offC;
#pragma unroll
  for (int mi = 0; mi < 2; ++mi)
#pragma unroll
    for (int ni = 0; ni < 2; ++ni)
#pragma unroll
      for (int r = 0; r < 16; ++r) {
        const int row = m0 + wm + mi * 32 + khi * 4 + (r & 3) + 8 * (r >> 2);
        const int col = n0 + wn + ni * 32 + l31;
        float v = acc[mi][ni][r];
        const long ci = (long)row * ldc + col;
        if constexpr (sizeof(OutT) == 2) {
          Cb[ci] = (OutT)f2h(v);
        } else {
          Cb[ci] = v;
        }
      }
}

// Small-tile GEMM for occupancy: 64x64 tile, 4 waves (each one 32x32 quadrant),
// BK=64, swizzled LDS (16 KB), grid 4x larger than 128-tile -> 4 blocks/CU.
// EPI: 0 plain, 1 -> 1-acc, 3 -> +ent/dep cols (ent pre-normalized by entnorm)
template <int EPI, typename OutT>
__global__ __launch_bounds__(256) void gemm_s(
    const unsigned short* __restrict__ A, const unsigned short* __restrict__ B,
    OutT* __restrict__ C,
    int K, int lda, int ldb, int ldc,
    int zbase, int zdiv,
    long sAi, long sAj, long sBi, long sBj, long sCi, long sCj,
    long sAz, long sBz, long sCz,
    const float* __restrict__ e0, const float* __restrict__ e1,
    const float* __restrict__ e2, const float* __restrict__ e3)
{
  __shared__ __align__(16) unsigned short lA[2][2048];
  __shared__ __align__(16) unsigned short lB[2][2048];

  const int z = blockIdx.z, gz = zbase + z;
  const int zi = gz / zdiv, zj = gz - zi * zdiv;
  const unsigned short* Ab = A + (long)zi * sAi + (long)zj * sAj + (long)z * sAz;
  const unsigned short* Bb = B + (long)zi * sBi + (long)zj * sBj + (long)z * sBz;
  const long offC = (long)zi * sCi + (long)zj * sCj + (long)z * sCz;

  const int m0 = blockIdx.y * 64, n0 = blockIdx.x * 64;
  const int tid = threadIdx.x, wave = tid >> 6, lane = tid & 63;
  const int wm = (wave >> 1) * 32, wn = (wave & 1) * 32;
  const int srow = lane >> 2;                       // staging row within wave's 16-row slice
  const int grow = wave * 16 + srow;                // global staging row 0..63
  const int scol = (((lane & 3) ^ ((grow >> 1) & 3))) * 8;
  const int l31 = lane & 31, khi = lane >> 5;
  const int sw2 = (l31 >> 1) & 3;

  f32x16 acc = {};

  for (int k0 = 0; k0 < K; k0 += 64) {
#pragma unroll
    for (int h = 0; h < 2; ++h) {
      gl_lds16(Ab + (long)(m0 + grow) * lda + (k0 + h * 32 + scol), &lA[h][wave * 512]);
      gl_lds16(Bb + (long)(n0 + grow) * ldb + (k0 + h * 32 + scol), &lB[h][wave * 512]);
    }
    __syncthreads();

    half8 af[4], bfr[4];
#pragma unroll
    for (int ks = 0; ks < 4; ++ks) {
      af[ks] = *(const half8*)&lA[ks >> 1][(wm + l31) * 32 + ((((ks & 1) * 2 + khi) ^ sw2) * 8)];
      bfr[ks] = *(const half8*)&lB[ks >> 1][(wn + l31) * 32 + ((((ks & 1) * 2 + khi) ^ sw2) * 8)];
    }
#pragma unroll
    for (int ks = 0; ks < 4; ++ks)
      acc = __builtin_amdgcn_mfma_f32_32x32x16_f16(af[ks], bfr[ks], acc, 0, 0, 0);
    __syncthreads();
  }

  OutT* Cb = C + offC;
#pragma unroll
  for (int r = 0; r < 16; ++r) {
    const int row = m0 + wm + khi * 4 + (r & 3) + 8 * (r >> 2);
    const int col = n0 + wn + l31;
    float v = acc[r];
    if constexpr (EPI == 1) v = 1.0f - v;
    if constexpr (EPI == 3)
      v += e0[(long)gz * 1024 + row] * e2[col] + e1[(long)gz * 1024 + row] * e3[col];
    const long ci = (long)row * ldc + col;
    if constexpr (sizeof(OutT) == 2) {
      Cb[ci] = (OutT)f2h(v);
    } else {
      Cb[ci] = v;
    }
  }
}

// sim GEMM: C(fp16) = A*B^T + APh, 128x128, LDS-staged, swizzled. (4/CU already.)
__global__ __launch_bounds__(256) void sim_gemm(
    const unsigned short* __restrict__ A, const unsigned short* __restrict__ B,
    unsigned short* __restrict__ C,
    const unsigned short* __restrict__ APh)
{
  __shared__ __align__(16) unsigned short lA[2][4096];
  __shared__ __align__(16) unsigned short lB[2][4096];

  const int gz = blockIdx.z;
  const int zi = gz >> 2, zj = gz & 3;
  const unsigned short* Ab = A + (long)zi * (TBB * DD) + zj * WBB;
  const unsigned short* Bb = B + (long)zi * (TBB * DD) + zj * WBB;
  unsigned short* Cb = C + (long)gz * TBB * TBB;

  const int m0 = blockIdx.y * 128, n0 = blockIdx.x * 128;
  const int tid = threadIdx.x, wave = tid >> 6, lane = tid & 63;
  const int wm = (wave >> 1) * 64, wn = (wave & 1) * 64;
  const int srow = lane >> 2;
  const int scol = ((lane & 3) ^ ((srow >> 1) & 3)) * 8;
  const int l31 = lane & 31, khi = lane >> 5;
  const int sw2 = (l31 >> 1) & 3;

  f32x16 acc[2][2] = {};

  for (int k0 = 0; k0 < WBB; k0 += 64) {
#pragma unroll
    for (int h = 0; h < 2; ++h)
#pragma unroll
      for (int t = 0; t < 2; ++t) {
        const int r = wave * 32 + t * 16 + srow;
        gl_lds16(Ab + (long)(m0 + r) * DD + (k0 + h * 32 + scol), &lA[h][wave * 1024 + t * 512]);
        gl_lds16(Bb + (long)(n0 + r) * DD + (k0 + h * 32 + scol), &lB[h][wave * 1024 + t * 512]);
      }
    __syncthreads();

    half8 af[2][4], bfr[2][4];
#pragma unroll
    for (int mi = 0; mi < 2; ++mi)
#pragma unroll
      for (int ks = 0; ks < 4; ++ks)
        af[mi][ks] = *(const half8*)&lA[ks >> 1][(wm + mi * 32 + l31) * 32 + ((((ks & 1) * 2 + khi) ^ sw2) * 8)];
#pragma unroll
    for (int ni = 0; ni < 2; ++ni)
#pragma unroll
      for (int ks = 0; ks < 4; ++ks)
        bfr[ni][ks] = *(const half8*)&lB[ks >> 1][(wn + ni * 32 + l31) * 32 + ((((ks & 1) * 2 + khi) ^ sw2) * 8)];

#pragma unroll
    for (int ks = 0; ks < 4; ++ks)
#pragma unroll
      for (int mi = 0; mi < 2; ++mi)
#pragma unroll
        for (int ni = 0; ni < 2; ++ni)
          acc[mi][ni] = __builtin_amdgcn_mfma_f32_32x32x16_f16(af[mi][ks], bfr[ni][ks], acc[mi][ni], 0, 0, 0);
    __syncthreads();
  }

#pragma unroll
  for (int mi = 0; mi < 2; ++mi)
#pragma unroll
    for (int ni = 0; ni < 2; ++ni)
#pragma unroll
      for (int r = 0; r < 16; ++r) {
        const int row = m0 + wm + mi * 32 + khi * 4 + (r & 3) + 8 * (r >> 2);
        const int col = n0 + wn + ni * 32 + l31;
        Cb[(long)row * TBB + col] = f2h(acc[mi][ni][r] + h2f(APh[(long)row * 1024 + col]));
      }
}

// ctx = (attw * (1+dep[k])) @ Vb, 64x64 tile.
// attw recomputed on the fly from sim(fp16) + per-row B = (m + ln L)*log2e:
//   attw = exp2(s*log2e - B)   (removes the 32MB wpre buffer entirely)
__global__ __launch_bounds__(256) void ctx_gemm_s(
    const unsigned short* __restrict__ simh, const float* __restrict__ dep,
    const float* __restrict__ Brow,
    const unsigned short* __restrict__ Vt, unsigned short* __restrict__ ctx)
{
  __shared__ __align__(16) unsigned short lA[2][2048];
  __shared__ __align__(16) unsigned short lB[2][2048];
  __shared__ __align__(16) unsigned short sDepH[1024];

  const int gz = blockIdx.z, zi = gz >> 2, zj = gz & 3;
  const int m0 = blockIdx.y * 64, n0 = blockIdx.x * 64;
  const int tid = threadIdx.x, wave = tid >> 6, lane = tid & 63;
  const int wm = (wave >> 1) * 32, wn = (wave & 1) * 32;
  const int srow = lane >> 2;
  const int grow = wave * 16 + srow;
  const int scol = ((lane & 3) ^ ((grow >> 1) & 3)) * 8;
  const int l31 = lane & 31, khi = lane >> 5;
  const int sw2 = (l31 >> 1) & 3;

#pragma unroll
  for (int p = 0; p < 4; ++p)
    sDepH[tid + p * 256] = f2h(1.f + dep[(long)gz * 1024 + tid + p * 256]);
  __syncthreads();

  // per-thread softmax row constants (row fixed per p across all k-steps)
  const float B0 = Brow[(long)gz * 1024 + m0 + (tid >> 3)];
  const float B1 = Brow[(long)gz * 1024 + m0 + 32 + (tid >> 3)];

  const unsigned short* Ab = simh + (long)gz * TBB * TBB;
  const unsigned short* Bb = Vt + (long)(zj * 256) * TT + (long)zi * 1024;

  f32x16 acc = {};

  for (int k0 = 0; k0 < 1024; k0 += 64) {
#pragma unroll
    for (int h = 0; h < 2; ++h)
      gl_lds16(Bb + (long)(n0 + grow) * TT + (k0 + h * 32 + scol), &lB[h][wave * 512]);
#pragma unroll
    for (int h = 0; h < 2; ++h)
#pragma unroll
      for (int p = 0; p < 2; ++p) {
        const int idx = p * 1024 + tid * 4;
        const int row = idx >> 5, col = idx & 31;
        const ushort4 wv = *(const ushort4*)(Ab + (long)(m0 + row) * 1024 + k0 + h * 32 + col);
        const float Bp = p ? B1 : B0;
        half4 ev;
        ev.x = (_Float16)exp2f(fmaf(h2f(wv.x), 1.4426950408889634f, -Bp));
        ev.y = (_Float16)exp2f(fmaf(h2f(wv.y), 1.4426950408889634f, -Bp));
        ev.z = (_Float16)exp2f(fmaf(h2f(wv.z), 1.4426950408889634f, -Bp));
        ev.w = (_Float16)exp2f(fmaf(h2f(wv.w), 1.4426950408889634f, -Bp));
        const half4 dv = *(const half4*)&sDepH[k0 + h * 32 + col];
        half4 pv = ev * dv;
        const int pcol = (((col >> 3) ^ ((row >> 1) & 3)) << 3) | (col & 7);
        *(half4*)&lA[h][row * 32 + pcol] = pv;
      }
    __syncthreads();

    half8 af[4], bfr[4];
#pragma unroll
    for (int ks = 0; ks < 4; ++ks) {
      af[ks] = *(const half8*)&lA[ks >> 1][(wm + l31) * 32 + ((((ks & 1) * 2 + khi) ^ sw2) * 8)];
      bfr[ks] = *(const half8*)&lB[ks >> 1][(wn + l31) * 32 + ((((ks & 1) * 2 + khi) ^ sw2) * 8)];
    }
#pragma unroll
    for (int ks = 0; ks < 4; ++ks)
      acc = __builtin_amdgcn_mfma_f32_32x32x16_f16(af[ks], bfr[ks], acc, 0, 0, 0);
    __syncthreads();
  }

  unsigned short* Cb = ctx + (long)gz * TBB * WBB;
#pragma unroll
  for (int r = 0; r < 16; ++r) {
    const int row = m0 + wm + khi * 4 + (r & 3) + 8 * (r >> 2);
    const int col = n0 + wn + l31;
    Cb[(long)row * WBB + col] = f2h(acc[r]);
  }
}

__global__ __launch_bounds__(256) void prepx_kernel(
    const float* __restrict__ x, unsigned short* __restrict__ xh,
    unsigned short* __restrict__ xu)
{
  const int t = blockIdx.x, tid = threadIdx.x;
  const float4 v = *((const float4*)(x + (long)t * DD) + tid);
  float ss = v.x * v.x + v.y * v.y + v.z * v.z + v.w * v.w;
  ss = waveSum(ss);
  __shared__ float red[4];
  if ((tid & 63) == 0) red[tid >> 6] = ss;
  __syncthreads();
  const float tot = red[0] + red[1] + red[2] + red[3];
  const float inv = 1.f / fmaxf(sqrtf(tot), 1e-12f);
  ushort4 h, u;
  h.x = f2h(v.x); h.y = f2h(v.y); h.z = f2h(v.z); h.w = f2h(v.w);
  u.x = f2h(v.x * inv); u.y = f2h(v.y * inv); u.z = f2h(v.z * inv); u.w = f2h(v.w * inv);
  *((ushort4*)(xh + (long)t * DD) + tid) = h;
  *((ushort4*)(xu + (long)t * DD) + tid) = u;
}

// Merged fp32->fp16 cast for Wq|Wk|Wv (-> Wh) and Wout (-> WoB). One launch.
__global__ __launch_bounds__(256) void castall_kernel(
    const float* __restrict__ Wq, const float* __restrict__ Wk,
    const float* __restrict__ Wv, const float* __restrict__ Wo,
    unsigned short* __restrict__ Wh, unsigned short* __restrict__ WoB)
{
  const long idx4 = ((long)blockIdx.x * 256 + threadIdx.x) * 4;
  const int which = (int)(idx4 >> 20);
  const long loc = idx4 & ((1L << 20) - 1);
  const float* src = (which == 0) ? Wq : ((which == 1) ? Wk : ((which == 2) ? Wv : Wo));
  unsigned short* dst = (which < 3) ? (Wh + idx4) : (WoB + loc);
  const float4 v = *(const float4*)(src + loc);
  ushort4 h;
  h.x = f2h(v.x); h.y = f2h(v.y); h.z = f2h(v.z); h.w = f2h(v.w);
  *(ushort4*)dst = h;
}

__global__ __launch_bounds__(256) void packw2_kernel(
    const float* __restrict__ W2, unsigned short* __restrict__ W2B,
    float* __restrict__ Ecol, float* __restrict__ Dcol)
{
  const int c = blockIdx.x, j = threadIdx.x;
  W2B[c * 256 + j] = f2h(W2[c * 258 + j]);
  if (j == 0) {
    Ecol[c] = W2[c * 258 + 256];
    Dcol[c] = W2[c * 258 + 257];
  }
}

__global__ __launch_bounds__(256) void ap_kernel(unsigned short* __restrict__ APh)
{
  const int p = blockIdx.x, tid = threadIdx.x;
#pragma unroll
  for (int t = 0; t < 4; ++t) {
    const int col = tid + t * 256;
    const int i = col >> 1;
    const float e = (2.0f * (float)i) / 1024.0f;
    // freq^-e = exp2(-e * log2(10000))
    const float ang = (float)p * exp2f(e * -13.287712379549449f);
    APh[(long)p * 1024 + col] = f2h((col & 1) ? cosf(ang) : sinf(ang));
  }
}

__global__ __launch_bounds__(256) void transpose_kernel(
    const unsigned short* __restrict__ V, unsigned short* __restrict__ Vt)
{
  __shared__ unsigned short tile[32][33];
  const int tx = threadIdx.x & 31, ty = threadIdx.x >> 5;
  const int c0 = blockIdx.x * 32;
  const int r0 = blockIdx.y * 32;
#pragma unroll
  for (int rr = ty; rr < 32; rr += 8)
    tile[rr][tx] = V[(long)(r0 + rr) * DD + c0 + tx];
  __syncthreads();
#pragma unroll
  for (int rr = ty; rr < 32; rr += 8)
    Vt[(long)(c0 + rr) * TT + r0 + tx] = tile[tx][rr];
}

// Wave-per-row stats: 4 rows/block, butterfly reductions, no LDS, no barriers,
// NO atomics (the round-1 atomicAdd to a single cache line serialized 16K RMWs
// across XCDs -> 212us). ent is written raw; entnorm normalizes per gz.
__global__ __launch_bounds__(256) void stats_kernel(
    const unsigned short* __restrict__ sim, const unsigned short* __restrict__ divb,
    float* __restrict__ dep, float* __restrict__ ent,
    float* __restrict__ Brow)
{
  const int gz = blockIdx.y, bi = gz >> 2;
  const int wave = threadIdx.x >> 6, lane = threadIdx.x & 63;
  const int q = blockIdx.x * 4 + wave;
  const unsigned short* srow = sim + ((long)gz * TBB + q) * TBB;
  const unsigned short* drow = divb + ((long)bi * TBB + q) * TBB;
  float s[16], d[16];
#pragma unroll
  for (int u = 0; u < 4; ++u) {
    const ushort4 sv = *(const ushort4*)(srow + u * 256 + lane * 4);
    const ushort4 dv = *(const ushort4*)(drow + u * 256 + lane * 4);
    s[u * 4 + 0] = h2f(sv.x); s[u * 4 + 1] = h2f(sv.y);
    s[u * 4 + 2] = h2f(sv.z); s[u * 4 + 3] = h2f(sv.w);
    d[u * 4 + 0] = h2f(dv.x); d[u * 4 + 1] = h2f(dv.y);
    d[u * 4 + 2] = h2f(dv.z); d[u * 4 + 3] = h2f(dv.w);
  }
  float m = s[0];
#pragma unroll
  for (int i = 1; i < 16; ++i) m = fmaxf(m, s[i]);
  m = bMax(m);
  const float mB = m * 1.4426950408889634f;
  float l = 0.f, ss = 0.f, dn = 0.f, ds = 0.f;
#pragma unroll
  for (int i = 0; i < 16; ++i) {
    const float e = exp2f(fmaf(s[i], 1.4426950408889634f, -mB));
    l += e; ss += e * s[i]; dn += e * d[i]; ds += d[i];
  }
  l = bSum(l); ss = bSum(ss); dn = bSum(dn); ds = bSum(ds);
  if (lane == 0) {
    const long o = (long)gz * TBB + q;
    const float Li = 1.f / l;
    const float lnL = logf(l);
    dep[o] = (dn * Li) / ds;
    ent[o] = (m + lnL - ss * Li) * 0.14426950408889634f;  // 1/ln(1024)
    Brow[o] = (m + lnL) * 1.4426950408889634f;
  }
}

__global__ __launch_bounds__(256) void entnorm_kernel(float* __restrict__ ent)
{
  const int gz = blockIdx.x, tid = threadIdx.x;
  float s = 0.f;
#pragma unroll
  for (int p = 0; p < 4; ++p) s += fabsf(ent[(long)gz * TBB + tid + p * 256]);
  s = waveSum(s);
  __shared__ float red[4];
  if ((tid & 63) == 0) red[tid >> 6] = s;
  __syncthreads();
  const float scale = 1.f / fmaxf(red[0] + red[1] + red[2] + red[3], 1e-12f);
#pragma unroll
  for (int p = 0; p < 4; ++p) ent[(long)gz * TBB + tid + p * 256] *= scale;
}

extern "C" void kernel_launch(void* const* d_in, const int* in_sizes, int n_in,
                              void* d_out, int out_size, void* d_ws, size_t ws_size,
                              hipStream_t stream)
{
  const float* x  = (const float*)d_in[0];
  const float* Wq = (const float*)d_in[1];
  const float* Wk = (const float*)d_in[2];
  const float* Wv = (const float*)d_in[3];
  const float* Wo = (const float*)d_in[4];
  const float* W2 = (const float*)d_in[5];

  char* ws = (char*)d_ws;
  size_t off = 0;
  auto take = [&](size_t bytes) -> void* {
    void* p = ws + off;
    off += (bytes + 255) & ~(size_t)255;
    return p;
  };
  unsigned short* QKV = (unsigned short*)take((size_t)3 * TT * DD * 2);
  unsigned short* xh  = (unsigned short*)take((size_t)TT * DD * 2);
  unsigned short* xu  = (unsigned short*)take((size_t)TT * DD * 2);
  unsigned short* Wh  = (unsigned short*)take((size_t)3 * DD * DD * 2);
  unsigned short* WoB = (unsigned short*)take((size_t)DD * DD * 2);
  unsigned short* W2B = (unsigned short*)take((size_t)256 * 256 * 2);
  float* Ecol = (float*)take(256 * 4);
  float* Dcol = (float*)take(256 * 4);
  unsigned short* APh = (unsigned short*)take((size_t)TBB * TBB * 2);
  unsigned short* divb = (unsigned short*)take((size_t)4 * TBB * TBB * 2);
  unsigned short* Vt = (unsigned short*)take((size_t)DD * TT * 2);
  unsigned short* simh = (unsigned short*)take((size_t)16 * TBB * TBB * 2);
  float* depb = (float*)take((size_t)16 * TBB * 4);
  float* entb = (float*)take((size_t)16 * TBB * 4);
  float* Brow = (float*)take((size_t)16 * TBB * 4);
  unsigned short* ctx = (unsigned short*)take((size_t)16 * TBB * WBB * 2);
  unsigned short* Y = (unsigned short*)take((size_t)TT * DD * 2);
  (void)ws_size; (void)in_sizes; (void)n_in; (void)out_size;

  prepx_kernel<<<TT, 256, 0, stream>>>(x, xh, xu);
  castall_kernel<<<(4 * DD * DD) / 1024, 256, 0, stream>>>(Wq, Wk, Wv, Wo, Wh, WoB);
  packw2_kernel<<<256, 256, 0, stream>>>(W2, W2B, Ecol, Dcol);
  ap_kernel<<<TBB, 256, 0, stream>>>(APh);

  // QKV projection: 128-tile core (3 blocks/CU, best measured)
  gemm_bt<0, unsigned short><<<dim3(DD / 128, TT / 128, 3), 256, 0, stream>>>(
      xh, Wh, QKV,
      DD, DD, DD, DD, 0, 1,
      0, 0, (long)DD * DD, 0, (long)TT * DD, 0,
      0, 0, 0, nullptr, nullptr, nullptr, nullptr);

  transpose_kernel<<<dim3(DD / 32, TT / 32), 256, 0, stream>>>(QKV + (size_t)2 * TT * DD, Vt);

  // div diagonal blocks: 1 - xu_i @ xu_i^T, fp16 out — 64-tile, 4 blocks/CU
  gemm_s<1, unsigned short><<<dim3(16, 16, 4), 256, 0, stream>>>(
      xu, xu, divb,
      DD, DD, DD, TBB, 0, 1,
      (long)TBB * DD, 0, (long)TBB * DD, 0, (long)TBB * TBB, 0,
      0, 0, 0, nullptr, nullptr, nullptr, nullptr);

  const unsigned short* Qh = QKV;
  const unsigned short* Kh = QKV + (size_t)TT * DD;

  // sim = Qb @ Kb^T + APh (fp16 out), all 16 blocks (4 blocks/CU already)
  sim_gemm<<<dim3(8, 8, 16), 256, 0, stream>>>(Qh, Kh, simh, APh);

  // per-row softmax stats: dep, ent(raw), B (no atomics)
  stats_kernel<<<dim3(TBB / 4, 16), 256, 0, stream>>>(simh, divb, depb, entb, Brow);
  entnorm_kernel<<<16, 256, 0, stream>>>(entb);

  // ctx = (exp2(s*log2e - B) * (1+dep[k])) @ Vb — 64-tile, attw recomputed in staging
  ctx_gemm_s<<<dim3(4, 16, 16), 256, 0, stream>>>(simh, depb, Brow, Vt, ctx);

  // y = [ctx | ent | dep] @ Wout2^T — 64-tile, 4 blocks/CU
  gemm_s<3, unsigned short><<<dim3(4, 16, 16), 256, 0, stream>>>(
      ctx, W2B, Y,
      WBB, WBB, WBB, DD, 0, 4,
      (long)4 * TBB * WBB, (long)TBB * WBB, 0, 0, (long)TBB * DD, (long)WBB,
      0, 0, 0, entb, depb, Ecol, Dcol);

  // out = Y @ Wout^T — 64-tile, 4 blocks/CU
  gemm_s<0, float><<<dim3(16, 64, 1), 256, 0, stream>>>(
      Y, WoB, (float*)d_out,
      DD, DD, DD, DD, 0, 1,
      0, 0, 0, 0, 0, 0,
      0, 0, 0, nullptr, nullptr, nullptr, nullptr);
}